// Round 4
// baseline (218.234 us; speedup 1.0000x reference)
//
#include <hip/hip_runtime.h>
#include <hip/hip_bf16.h>

// y = x + 0.2 * (8-neighbor sum), fp32, (8,16,1024,1024), zero-padded edges.
//
// R4: kill the VMEM-request bottleneck.
//  - Edge values via __shfl_up/__shfl_down (register exchange) instead of 512
//    scalar global loads per row; only wave-boundary lanes (2/wave) load.
//  - ROWS=32: halo read amplification 34/32 = 1.0625x.
//  - Per-row horizontal 3-sums precomputed ONCE per row (f4 s) and reused as
//    top/middle/bottom contributions: out = c + a*(t_s + m_s + b_s - c).
//  - Explicit one-iteration-ahead prefetch (pend holds raw row i+1 while the
//    load for row i+2 is issued before row i's compute).
//  - XCD-chunked block swizzle (nwg=4096, %8==0 -> simple bijection) so tiles
//    sharing halo rows land on the same XCD's L2.

#define ALPHA 0.2f
#define ROWS 32
#define W 1024
#define H 1024

typedef float f4 __attribute__((ext_vector_type(4)));

struct Pend { f4 c; float eL, eR; };

__device__ __forceinline__ void loadrow(const float* __restrict__ p, int w,
                                        int lane, Pend& P) {
    P.c = *reinterpret_cast<const f4*>(p + w);
    P.eL = 0.0f; P.eR = 0.0f;
    if (lane == 0 && w > 0)       P.eL = p[w - 1];   // divergent: 1 lane/wave
    if (lane == 63 && w + 4 < W)  P.eR = p[w + 4];   // divergent: 1 lane/wave
}

__device__ __forceinline__ void convert(const Pend& P, int lane, f4& s, f4& c) {
    const float l = __shfl_up(P.c.w, 1);     // lane i <- lane i-1's last elem
    const float r = __shfl_down(P.c.x, 1);   // lane i <- lane i+1's first elem
    const float eL = (lane == 0)  ? P.eL : l;
    const float eR = (lane == 63) ? P.eR : r;
    c = P.c;
    s.x = eL    + P.c.x + P.c.y;
    s.y = P.c.x + P.c.y + P.c.z;
    s.z = P.c.y + P.c.z + P.c.w;
    s.w = P.c.z + P.c.w + eR;
}

__global__ __launch_bounds__(256)
void contamination_kernel(const float* __restrict__ x, float* __restrict__ y) {
    const int tilesPerImg = H / ROWS;              // 32
    const int cpx = gridDim.x >> 3;                // chunk per XCD (4096/8)
    const int bid = blockIdx.x;
    const int tile = (bid & 7) * cpx + (bid >> 3); // bijective XCD swizzle

    const int img  = tile / tilesPerImg;
    const int trow = tile - img * tilesPerImg;
    const int h0   = trow * ROWS;
    const size_t base = ((size_t)img * H + (size_t)h0) * (size_t)W;

    const int tid  = threadIdx.x;
    const int lane = tid & 63;
    const int w    = tid * 4;

    const float* __restrict__ row  = x + base;
    float* __restrict__       orow = y + base;

    f4 t_s, m_s, m_c;
    if (h0 > 0) {
        Pend P; loadrow(row - W, w, lane, P);
        f4 dc; convert(P, lane, t_s, dc);
    } else {
        t_s.x = t_s.y = t_s.z = t_s.w = 0.0f;
    }

    { Pend P; loadrow(row, w, lane, P); convert(P, lane, m_s, m_c); }

    Pend pend;
    loadrow(row + W, w, lane, pend);               // row h0+1, always in bounds

#pragma unroll
    for (int i = 0; i < ROWS; ++i) {
        f4 b_s, b_c;
        if (h0 + i + 1 < H) {
            convert(pend, lane, b_s, b_c);
        } else {                                   // only last iter of last tile
            b_s.x = b_s.y = b_s.z = b_s.w = 0.0f;
            b_c = b_s;
        }

        if (i < ROWS - 1 && h0 + i + 2 < H)        // prefetch next b-row
            loadrow(row + 2 * W, w, lane, pend);

        f4 o;
#pragma unroll
        for (int j = 0; j < 4; ++j) {
            const float nb = t_s[j] + b_s[j] + m_s[j] - m_c[j];
            o[j] = fmaf(ALPHA, nb, m_c[j]);
        }
        __builtin_nontemporal_store(o, reinterpret_cast<f4*>(orow + w));

        t_s = m_s; m_s = b_s; m_c = b_c;
        row += W; orow += W;
    }
}

extern "C" void kernel_launch(void* const* d_in, const int* in_sizes, int n_in,
                              void* d_out, int out_size, void* d_ws, size_t ws_size,
                              hipStream_t stream) {
    const float* x = (const float*)d_in[0];
    float* y = (float*)d_out;

    const int n = in_sizes[0];                 // B*C*H*W
    const int blocks = (n / W) / ROWS;         // 4096

    contamination_kernel<<<dim3(blocks), dim3(W / 4), 0, stream>>>(x, y);
}

// Round 5
// 213.686 us; speedup vs baseline: 1.0213x; 1.0213x over previous
//
#include <hip/hip_runtime.h>
#include <hip/hip_bf16.h>

// y = x + 0.2 * (8-neighbor sum), fp32, (8,16,1024,1024), zero-padded edges.
//
// R5: R3 structure (plain scalar edge loads — they're L1 hits) plus:
//  - ROWS=32: halo read amplification 34/32 = 1.0625x (R3 was 1.125x).
//  - Explicit 2-row-ahead register pipeline (p1,p2): two row loads in flight
//    per wave at all times (R3 compiled to VGPR=16 -> ~no MLP, BW stuck at
//    5.4 TB/s).
//  - Horizontal 3-sums computed once per row (6 adds) and rotated through
//    t_s/m_s/b_s; out = center + 0.2*(t_s + m_s + b_s - center).
//  - Bottom-boundary rows flow through the pipeline as zeros: uniform loop.
//  - NO shfl edge exchange, NO XCD swizzle (R4 regression suspects).

#define ALPHA 0.2f
#define ROWS 32
#define W 1024
#define H 1024

typedef float f4 __attribute__((ext_vector_type(4)));

__device__ __forceinline__ void load6(const float* __restrict__ p, int w,
                                      float v[6]) {
    const f4 c = *reinterpret_cast<const f4*>(p + w);
    v[0] = (w > 0) ? p[w - 1] : 0.0f;      // diverges only on thread 0
    v[1] = c.x; v[2] = c.y; v[3] = c.z; v[4] = c.w;
    v[5] = (w + 4 < W) ? p[w + 4] : 0.0f;  // diverges only on thread 255
}

__device__ __forceinline__ void sums(const float v[6], f4& s, f4& c) {
    const float p12 = v[1] + v[2], p34 = v[3] + v[4];
    s.x = v[0] + p12;  s.y = p12 + v[3];
    s.z = v[2] + p34;  s.w = p34 + v[5];
    c.x = v[1]; c.y = v[2]; c.z = v[3]; c.w = v[4];
}

__global__ __launch_bounds__(256)
void contamination_kernel(const float* __restrict__ x, float* __restrict__ y) {
    const int tilesPerImg = H / ROWS;                // 32
    const int tile = blockIdx.x;
    const int img  = tile / tilesPerImg;
    const int h0   = (tile - img * tilesPerImg) * ROWS;
    const size_t base = ((size_t)img * H + (size_t)h0) * (size_t)W;
    const int w = threadIdx.x * 4;

    const float* __restrict__ row  = x + base;
    float* __restrict__       orow = y + base;

    f4 t_s, m_s, m_c;
    {
        float v[6];
        if (h0 > 0) {
            load6(row - W, w, v);
            f4 dc; sums(v, t_s, dc);
        } else {
            t_s.x = t_s.y = t_s.z = t_s.w = 0.0f;
        }
        load6(row, w, v);
        sums(v, m_s, m_c);
    }

    // 2-deep raw-row pipeline: p1 = row h0+1, p2 = row h0+2 (always in-bounds
    // since ROWS=32 and tiles align: h0+2 <= H-30).
    float p1[6], p2[6];
    load6(row + W, w, p1);
    load6(row + 2 * W, w, p2);

#pragma unroll
    for (int i = 0; i < ROWS; ++i) {
        f4 b_s, b_c;
        sums(p1, b_s, b_c);                          // row h0+i+1 (or zeros)

#pragma unroll
        for (int j = 0; j < 6; ++j) p1[j] = p2[j];   // rotate pipeline

        if (i < ROWS - 2 && h0 + i + 3 < H) {        // prefetch row h0+i+3
            load6(row + 3 * W, w, p2);
        } else {
#pragma unroll
            for (int j = 0; j < 6; ++j) p2[j] = 0.0f; // OOB rows -> zeros
        }

        f4 o;
#pragma unroll
        for (int j = 0; j < 4; ++j)
            o[j] = fmaf(ALPHA, t_s[j] + m_s[j] + b_s[j] - m_c[j], m_c[j]);
        __builtin_nontemporal_store(o, reinterpret_cast<f4*>(orow + w));

        t_s = m_s; m_s = b_s; m_c = b_c;
        row += W; orow += W;
    }
}

extern "C" void kernel_launch(void* const* d_in, const int* in_sizes, int n_in,
                              void* d_out, int out_size, void* d_ws, size_t ws_size,
                              hipStream_t stream) {
    const float* x = (const float*)d_in[0];
    float* y = (float*)d_out;

    const int n = in_sizes[0];                 // B*C*H*W
    const int blocks = (n / W) / ROWS;         // 4096

    contamination_kernel<<<dim3(blocks), dim3(W / 4), 0, stream>>>(x, y);
}